// Round 1
// baseline (145.879 us; speedup 1.0000x reference)
//
#include <hip/hip_runtime.h>
#include <math.h>

// Chamfer distance, N=16384 points per cloud (8*2048), 3-D fp32.
// d2(i,j) = n_i + n_j - 2*dot = n_i + 2*(c_j - dot),  c = 0.5*||p||^2
// -> inner loop per pair: 3 fma + 1 min (h_i drops out of the argmin).
#define N_PTS 16384
#define TPB   256
#define IP    4                       // query points per thread (registers)
#define IBLK  (N_PTS / (TPB * IP))    // 16 i-blocks
#define JT    1024                    // target tile in LDS (16 KB)
#define JS    (N_PTS / JT)            // 16 j-splits, combined via atomicMin

__global__ __launch_bounds__(TPB) void chamfer_pack(
    const float* __restrict__ p1, const float* __restrict__ p2,
    float4* __restrict__ P, unsigned int* __restrict__ dmin) {
  int id = blockIdx.x * TPB + threadIdx.x;          // 0 .. 2*N_PTS-1
  const float* src = (id < N_PTS) ? p1 : p2;
  int k = (id < N_PTS) ? id : (id - N_PTS);
  float x = src[3 * k + 0], y = src[3 * k + 1], z = src[3 * k + 2];
  P[id] = make_float4(x, y, z, 0.5f * (x * x + y * y + z * z));
  dmin[id] = 0x7F800000u;  // +inf bits (d2 >= 0, so uint order == float order)
}

__global__ __launch_bounds__(TPB) void chamfer_min(
    const float4* __restrict__ P, unsigned int* __restrict__ dmin) {
  __shared__ float4 tile[JT];
  const int dir = blockIdx.z;                         // 0: query=pc1, 1: query=pc2
  const float4* __restrict__ Q = P + (size_t)dir * N_PTS;
  const float4* __restrict__ T = P + (size_t)(1 - dir) * N_PTS;
  unsigned int* __restrict__ out = dmin + (size_t)dir * N_PTS;

  const int jbase = blockIdx.x * JT;
  for (int t = threadIdx.x; t < JT; t += TPB)
    tile[t] = T[jbase + t];
  __syncthreads();

  const int i0 = blockIdx.y * (TPB * IP) + threadIdx.x * IP;
  float nx[IP], ny[IP], nz[IP], cw[IP], vmin[IP];
#pragma unroll
  for (int k = 0; k < IP; ++k) {
    float4 p = Q[i0 + k];
    nx[k] = -p.x; ny[k] = -p.y; nz[k] = -p.z; cw[k] = p.w;
    vmin[k] = INFINITY;
  }

  // 2-way j unroll so fminf(vmin, fminf(va, vb)) folds to v_min3_f32:
  // 3.5 VALU inst per pair.
  for (int j = 0; j < JT; j += 2) {
    float4 qa = tile[j];
    float4 qb = tile[j + 1];
#pragma unroll
    for (int k = 0; k < IP; ++k) {
      float va = fmaf(nx[k], qa.x, qa.w);
      va = fmaf(ny[k], qa.y, va);
      va = fmaf(nz[k], qa.z, va);
      float vb = fmaf(nx[k], qb.x, qb.w);
      vb = fmaf(ny[k], qb.y, vb);
      vb = fmaf(nz[k], qb.z, vb);
      vmin[k] = fminf(vmin[k], fminf(va, vb));
    }
  }

#pragma unroll
  for (int k = 0; k < IP; ++k) {
    float d2 = fmaxf(0.f, 2.f * (cw[k] + vmin[k]));   // clamp -> non-negative
    atomicMin(&out[i0 + k], __float_as_uint(d2));     // monotone on uint bits
  }
}

__global__ __launch_bounds__(TPB) void chamfer_reduce(
    const unsigned int* __restrict__ dmin, float* __restrict__ outp) {
  float s = 0.f;
  for (int i = threadIdx.x; i < 2 * N_PTS; i += TPB)
    s += sqrtf(__uint_as_float(dmin[i]));
#pragma unroll
  for (int off = 32; off > 0; off >>= 1)
    s += __shfl_down(s, off, 64);
  __shared__ float partial[TPB / 64];
  if ((threadIdx.x & 63) == 0) partial[threadIdx.x >> 6] = s;
  __syncthreads();
  if (threadIdx.x == 0) {
    float t = 0.f;
    for (int w = 0; w < TPB / 64; ++w) t += partial[w];
    // mean(dist1) + mean(dist2) = (sum of all 2N nn-distances) / N
    outp[0] = t / (float)N_PTS;
  }
}

extern "C" void kernel_launch(void* const* d_in, const int* in_sizes, int n_in,
                              void* d_out, int out_size, void* d_ws, size_t ws_size,
                              hipStream_t stream) {
  const float* pc1 = (const float*)d_in[0];
  const float* pc2 = (const float*)d_in[1];
  // ws layout: P[2N] float4 (512 KB) | dmin[2N] uint (128 KB)
  float4* P = (float4*)d_ws;
  unsigned int* dmin = (unsigned int*)((char*)d_ws + (size_t)2 * N_PTS * sizeof(float4));

  chamfer_pack<<<(2 * N_PTS) / TPB, TPB, 0, stream>>>(pc1, pc2, P, dmin);
  chamfer_min<<<dim3(JS, IBLK, 2), TPB, 0, stream>>>(P, dmin);
  chamfer_reduce<<<1, TPB, 0, stream>>>(dmin, (float*)d_out);
}

// Round 2
// 99.906 us; speedup vs baseline: 1.4602x; 1.4602x over previous
//
#include <hip/hip_runtime.h>
#include <math.h>

// Chamfer distance, N=16384 points per cloud (8*2048), 3-D fp32.
// d2(i,j) = n_i + n_j - 2*dot = n_i + 2*(c_j - dot),  c = 0.5*||p||^2
// Inner loop: 3 fma per pair + 1 v_min3 per 2 pairs (forced via asm —
// fminf in IEEE mode emits v_max canonicalization + no min3: 2.1x bloat).
#define N_PTS 16384
#define TPB   256
#define IP    4                       // query points per thread (registers)
#define IBLK  (N_PTS / (TPB * IP))    // 16 i-blocks
#define JT    512                     // tile in LDS (8 KB)
#define JS    (N_PTS / JT)            // 32 j-splits, combined via atomicMin
#define REDB  64                      // reduce blocks

__global__ __launch_bounds__(TPB) void chamfer_pack(
    const float* __restrict__ p1, const float* __restrict__ p2,
    float4* __restrict__ P, unsigned int* __restrict__ dmin,
    float* __restrict__ outp) {
  int id = blockIdx.x * TPB + threadIdx.x;          // 0 .. 2*N_PTS-1
  const float* src = (id < N_PTS) ? p1 : p2;
  int k = (id < N_PTS) ? id : (id - N_PTS);
  float x = src[3 * k + 0], y = src[3 * k + 1], z = src[3 * k + 2];
  P[id] = make_float4(x, y, z, 0.5f * (x * x + y * y + z * z));
  dmin[id] = 0x7F800000u;  // +inf bits (d2 >= 0, so uint order == float order)
  if (id == 0) outp[0] = 0.f;        // harness poisons d_out with 0xAA
}

__global__ __launch_bounds__(TPB) void chamfer_min(
    const float4* __restrict__ P, unsigned int* __restrict__ dmin) {
  __shared__ float4 tile[JT];
  const int dir = blockIdx.z;                         // 0: query=pc1, 1: query=pc2
  const float4* __restrict__ Q = P + (size_t)dir * N_PTS;
  const float4* __restrict__ T = P + (size_t)(1 - dir) * N_PTS;
  unsigned int* __restrict__ out = dmin + (size_t)dir * N_PTS;

  const int jbase = blockIdx.x * JT;
  for (int t = threadIdx.x; t < JT; t += TPB)
    tile[t] = T[jbase + t];
  __syncthreads();

  const int i0 = blockIdx.y * (TPB * IP) + threadIdx.x * IP;
  float nx[IP], ny[IP], nz[IP], cw[IP], vmin[IP];
#pragma unroll
  for (int k = 0; k < IP; ++k) {
    float4 p = Q[i0 + k];
    nx[k] = -p.x; ny[k] = -p.y; nz[k] = -p.z; cw[k] = p.w;
    vmin[k] = INFINITY;
  }

  // min_j (c_j - dot_ij); h_i drops out of the argmin.
#pragma unroll 8
  for (int j = 0; j < JT; j += 2) {
    float4 qa = tile[j];
    float4 qb = tile[j + 1];
#pragma unroll
    for (int k = 0; k < IP; ++k) {
      float va = fmaf(nx[k], qa.x, qa.w);
      va = fmaf(ny[k], qa.y, va);
      va = fmaf(nz[k], qa.z, va);
      float vb = fmaf(nx[k], qb.x, qb.w);
      vb = fmaf(ny[k], qb.y, vb);
      vb = fmaf(nz[k], qb.z, vb);
      // vmin = min(vmin, va, vb) in ONE instruction (data is NaN-free).
      asm("v_min3_f32 %0, %1, %2, %3"
          : "=v"(vmin[k]) : "v"(va), "v"(vb), "v"(vmin[k]));
    }
  }

#pragma unroll
  for (int k = 0; k < IP; ++k) {
    float d2 = fmaxf(0.f, 2.f * (cw[k] + vmin[k]));   // clamp -> non-negative
    atomicMin(&out[i0 + k], __float_as_uint(d2));     // monotone on uint bits
  }
}

__global__ __launch_bounds__(TPB) void chamfer_reduce(
    const unsigned int* __restrict__ dmin, float* __restrict__ outp) {
  float s = 0.f;
  for (int i = blockIdx.x * TPB + threadIdx.x; i < 2 * N_PTS; i += REDB * TPB)
    s += sqrtf(__uint_as_float(dmin[i]));
#pragma unroll
  for (int off = 32; off > 0; off >>= 1)
    s += __shfl_down(s, off, 64);
  __shared__ float partial[TPB / 64];
  if ((threadIdx.x & 63) == 0) partial[threadIdx.x >> 6] = s;
  __syncthreads();
  if (threadIdx.x == 0) {
    float t = 0.f;
    for (int w = 0; w < TPB / 64; ++w) t += partial[w];
    // mean(dist1) + mean(dist2) = (sum of all 2N nn-distances) / N
    atomicAdd(outp, t * (1.0f / (float)N_PTS));
  }
}

extern "C" void kernel_launch(void* const* d_in, const int* in_sizes, int n_in,
                              void* d_out, int out_size, void* d_ws, size_t ws_size,
                              hipStream_t stream) {
  const float* pc1 = (const float*)d_in[0];
  const float* pc2 = (const float*)d_in[1];
  // ws layout: P[2N] float4 (512 KB) | dmin[2N] uint (128 KB)
  float4* P = (float4*)d_ws;
  unsigned int* dmin = (unsigned int*)((char*)d_ws + (size_t)2 * N_PTS * sizeof(float4));
  float* outp = (float*)d_out;

  chamfer_pack<<<(2 * N_PTS) / TPB, TPB, 0, stream>>>(pc1, pc2, P, dmin, outp);
  chamfer_min<<<dim3(JS, IBLK, 2), TPB, 0, stream>>>(P, dmin);
  chamfer_reduce<<<REDB, TPB, 0, stream>>>(dmin, outp);
}